// Round 7
// baseline (328.528 us; speedup 1.0000x reference)
//
#include <hip/hip_runtime.h>

#define BSZ 8
#define TLEN 2048
#define CDIM 768
#define LCH 16
#define NCH (TLEN / LCH)

typedef __attribute__((ext_vector_type(4))) float f32x4;
typedef __attribute__((ext_vector_type(8))) short bf16x8;   // 8 bf16 = 4 VGPRs (MFMA operand)
typedef __attribute__((ext_vector_type(4))) unsigned short us4;
typedef __attribute__((ext_vector_type(4))) float float4v;

__device__ __forceinline__ unsigned short f2bf(float f) {
    unsigned int u = __float_as_uint(f);
    u += 0x7fffu + ((u >> 16) & 1u);   // RNE
    return (unsigned short)(u >> 16);
}
__device__ __forceinline__ float bf2f(unsigned short h) {
    return __uint_as_float(((unsigned int)h) << 16);
}

// async global->LDS, 16B per lane; LDS dest = base + lane*16 (wave-linear)
#define GLD16(g, l)                                                          \
    __builtin_amdgcn_global_load_lds(                                        \
        (const __attribute__((address_space(1))) unsigned int*)(g),          \
        (__attribute__((address_space(3))) unsigned int*)(l), 16, 0, 0)

// ---------------------------------------------------------------------------
// split f32 -> (hi, lo) bf16, 4 elements/thread. n4 = n/4.
// ---------------------------------------------------------------------------
__global__ __launch_bounds__(256) void split_f32(const float* __restrict__ src,
                                                 unsigned short* __restrict__ hi,
                                                 unsigned short* __restrict__ lo,
                                                 int n4) {
    int i = blockIdx.x * 256 + threadIdx.x;
    if (i >= n4) return;
    float4v f = ((const float4v*)src)[i];
    us4 h, l;
    #pragma unroll
    for (int j = 0; j < 4; ++j) {
        unsigned short hh = f2bf(f[j]);
        h[j] = hh;
        l[j] = f2bf(f[j] - bf2f(hh));
    }
    ((us4*)hi)[i] = h;
    ((us4*)lo)[i] = l;
}

// ---------------------------------------------------------------------------
// Split-precision MFMA GEMM (NT): out[m,n] = sum_k A[m,k]*W[n,k], A=Ah+Al,
// W=Wh+Wl (bf16), fp32 accum via 3 MFMAs (hh, hl, lh). N=K=CDIM.
// 256x192 tile, BK=32, 8 waves. Counted-vmcnt pipeline:
//   A planes (HBM-latency): 3 buffers, staged depth-2, waves 0-3, vmcnt(8)
//   B planes (L2-resident weights): 2 buffers, depth-1, waves 4-7, vmcnt(0)
// Raw s_barrier; LDS = 3*32KB + 2*24KB = 144KB; grid 256 blocks = 1/CU.
// LDS layout: Abuf i @ i*32768 {Ah@0, Al@16384}; Bbuf i @ 98304+i*24576
// {Bh@0, Bl@12288}. Same write/read swizzle involution as rounds 5-6.
// mode 1: sigmoid epilogue.
// ---------------------------------------------------------------------------
__global__ __launch_bounds__(512, 2) void gemm_mfma_split(
    const unsigned short* __restrict__ Ah, const unsigned short* __restrict__ Al,
    const unsigned short* __restrict__ Wh, const unsigned short* __restrict__ Wl,
    float* __restrict__ out, int mpx, int mode) {
    constexpr int K = CDIM, N = CDIM;
    constexpr int NT = K / 32;   // 24
    __shared__ __align__(16) char smem[147456];

    const int tid  = threadIdx.x;
    const int lane = tid & 63;
    const int wid  = tid >> 6;

    const int bid = blockIdx.x;
    const int xcd = bid & 7;
    const int lj  = bid >> 3;
    const int m0 = (xcd * mpx + (lj >> 2)) * 256;
    const int n0 = (lj & 3) * 192;

    // ---- staging role: waves 0-3 stage A (Ah+Al, 64 rows each, 8 loads/step);
    //      waves 4-7 stage B (Bh+Bl, 48 rows each, 6 loads/step)
    const bool isA = (wid < 4);
    const int  aw  = wid & 3;
    const char* gbh = (const char*)(isA ? Ah : Wh);
    const char* gbl = (const char*)(isA ? Al : Wl);
    const int rowstart = isA ? (m0 + aw * 64) : (n0 + aw * 48);
    // per-lane pre-swizzled global byte offset; selector == (lane>>4)&3
    const int gq = (lane & 3) ^ ((lane >> 4) & 3);
    const size_t gofs = (size_t)(rowstart + (lane >> 2)) * (K * 2) + gq * 16;
    const int lofs = (isA ? aw * 4096 : aw * 3072) + lane * 16;
    const int losep = isA ? 16384 : 12288;       // hi->lo plane LDS separation

    auto STAGE = [&](int bufbase, int k0) {
        char* lbh = &smem[bufbase] + lofs;
        const char* gh = gbh + gofs + (size_t)k0 * 2;
        const char* gl = gbl + gofs + (size_t)k0 * 2;
        #pragma unroll
        for (int q = 0; q < 4; ++q) {
            if (isA || q < 3) {                  // wave-uniform
                GLD16(gh + q * 24576, lbh + q * 1024);
                GLD16(gl + q * 24576, lbh + losep + q * 1024);
            }
        }
    };

    // ---- compute role: wr = wid>>1 (64-row group), wc = wid&1 (96-col group)
    const int wr = wid >> 1, wc = wid & 1;
    const int rl   = lane & 15;
    const int kofs = (((lane >> 4) ^ ((rl >> 2) & 3)) << 4);

    f32x4 acc[4][6];
    #pragma unroll
    for (int i = 0; i < 4; ++i)
        #pragma unroll
        for (int j = 0; j < 6; ++j)
            acc[i][j] = (f32x4){0.f, 0.f, 0.f, 0.f};

    auto COMPUTE = [&](int ab, int bb) {
        bf16x8 a_h[4], a_l[4], b_h[6], b_l[6];
        #pragma unroll
        for (int fi = 0; fi < 4; ++fi) {
            const int off = ab + (wr * 64 + fi * 16 + rl) * 64 + kofs;
            a_h[fi] = *(const bf16x8*)(&smem[0] + off);
            a_l[fi] = *(const bf16x8*)(&smem[0] + off + 16384);
        }
        #pragma unroll
        for (int fj = 0; fj < 6; ++fj) {
            const int off = bb + (wc * 96 + fj * 16 + rl) * 64 + kofs;
            b_h[fj] = *(const bf16x8*)(&smem[0] + off);
            b_l[fj] = *(const bf16x8*)(&smem[0] + off + 12288);
        }
        __builtin_amdgcn_s_setprio(1);
        #pragma unroll
        for (int fi = 0; fi < 4; ++fi)
            #pragma unroll
            for (int fj = 0; fj < 6; ++fj)
                acc[fi][fj] = __builtin_amdgcn_mfma_f32_16x16x32_bf16(a_h[fi], b_h[fj], acc[fi][fj], 0, 0, 0);
        #pragma unroll
        for (int fi = 0; fi < 4; ++fi)
            #pragma unroll
            for (int fj = 0; fj < 6; ++fj)
                acc[fi][fj] = __builtin_amdgcn_mfma_f32_16x16x32_bf16(a_h[fi], b_l[fj], acc[fi][fj], 0, 0, 0);
        #pragma unroll
        for (int fi = 0; fi < 4; ++fi)
            #pragma unroll
            for (int fj = 0; fj < 6; ++fj)
                acc[fi][fj] = __builtin_amdgcn_mfma_f32_16x16x32_bf16(a_l[fi], b_h[fj], acc[fi][fj], 0, 0, 0);
        __builtin_amdgcn_s_setprio(0);
    };

    // ---- prologue: A depth-2, B depth-1
    if (isA) { STAGE(0, 0); STAGE(32768, 32); }
    else     { STAGE(98304, 0); }
    if (isA) asm volatile("s_waitcnt vmcnt(8)" ::: "memory");
    else     asm volatile("s_waitcnt vmcnt(0)" ::: "memory");
    __builtin_amdgcn_s_barrier();

    // ---- main loop, unrolled x6 so buffer indices are compile-time
    for (int tb = 0; tb < NT; tb += 6) {
        #pragma unroll
        for (int tt = 0; tt < 6; ++tt) {
            const int t = tb + tt;
            if (isA) {
                if (t + 2 < NT) STAGE(((tt + 2) % 3) * 32768, (t + 2) * 32);
            } else {
                if (t + 1 < NT) STAGE(98304 + ((tt + 1) & 1) * 24576, (t + 1) * 32);
            }
            COMPUTE((tt % 3) * 32768, 98304 + (tt & 1) * 24576);
            if (isA && t + 2 < NT) asm volatile("s_waitcnt vmcnt(8)" ::: "memory");
            else                   asm volatile("s_waitcnt vmcnt(0)" ::: "memory");
            __builtin_amdgcn_s_barrier();
        }
    }

    // epilogue: D frag mapping col=lane&15, row=(lane>>4)*4+r
    const int erow = m0 + wr * 64 + ((lane >> 4) << 2);
    const int ecol = n0 + wc * 96 + rl;
    #pragma unroll
    for (int fi = 0; fi < 4; ++fi)
        #pragma unroll
        for (int fj = 0; fj < 6; ++fj)
            #pragma unroll
            for (int r = 0; r < 4; ++r) {
                float vv = acc[fi][fj][r];
                if (mode == 1) vv = 1.0f / (1.0f + __expf(-vv));
                out[(size_t)(erow + fi * 16 + r) * N + (ecol + fj * 16)] = vv;
            }
}

// ---------------------------------------------------------------------------
// WKV (math verified rounds 2-6)
// ---------------------------------------------------------------------------
#define WKV_STEP(a, bb, p, kt, vt, w)                \
    {                                                \
        const float pn = fmaxf((p) - (w), (kt));     \
        const float e1 = __expf((p) - (w) - pn);     \
        const float e2 = __expf((kt) - pn);          \
        (a)  = e1 * (a)  + e2 * (vt);                \
        (bb) = e1 * (bb) + e2;                       \
        (p)  = pn;                                   \
    }

__global__ __launch_bounds__(256) void wkv_phase1(
    const float* __restrict__ k, const float* __restrict__ v,
    const float* __restrict__ decay,
    float* __restrict__ Sfa, float* __restrict__ Sfb, float* __restrict__ Sfp,
    float* __restrict__ Sba, float* __restrict__ Sbb, float* __restrict__ Sbp) {
    const int c = blockIdx.x * 256 + threadIdx.x;
    const int j = blockIdx.y;
    const int b = blockIdx.z;
    const float w = decay[c] * (1.0f / (float)TLEN);

    const size_t base = ((size_t)b * TLEN + (size_t)j * LCH) * CDIM + c;
    float kt[LCH], vt[LCH];
    #pragma unroll
    for (int i = 0; i < LCH; ++i) {
        kt[i] = k[base + (size_t)i * CDIM];
        vt[i] = v[base + (size_t)i * CDIM];
    }

    const size_t idx = ((size_t)b * NCH + j) * CDIM + c;

    float a = 0.0f, bb = 0.0f, p = -1e38f;
    #pragma unroll
    for (int i = 0; i < LCH; ++i) WKV_STEP(a, bb, p, kt[i], vt[i], w);
    Sfa[idx] = a; Sfb[idx] = bb; Sfp[idx] = p;

    a = 0.0f; bb = 0.0f; p = -1e38f;
    #pragma unroll
    for (int i = LCH - 1; i >= 0; --i) WKV_STEP(a, bb, p, kt[i], vt[i], w);
    Sba[idx] = a; Sbb[idx] = bb; Sbp[idx] = p;
}

#define WKV_COMBINE(a, bb, p, as, bs, ps, wL)        \
    {                                                \
        const float pn = fmaxf((p) - (wL), (ps));    \
        const float e1 = __expf((p) - (wL) - pn);    \
        const float e2 = __expf((ps) - pn);          \
        (a)  = e1 * (a)  + e2 * (as);                \
        (bb) = e1 * (bb) + e2 * (bs);                \
        (p)  = pn;                                   \
    }

// blockIdx.z selects direction (0=forward, 1=backward)
__global__ __launch_bounds__(64) void wkv_phase2(
    const float* __restrict__ Sfa, const float* __restrict__ Sfb, const float* __restrict__ Sfp,
    const float* __restrict__ Sba, const float* __restrict__ Sbb, const float* __restrict__ Sbp,
    const float* __restrict__ decay,
    float* __restrict__ Lina, float* __restrict__ Linb, float* __restrict__ Linp,
    float* __restrict__ Rina, float* __restrict__ Rinb, float* __restrict__ Rinp) {
    const int c = blockIdx.x * 64 + threadIdx.x;
    const int b = blockIdx.y;
    const float wL = decay[c] * ((float)LCH / (float)TLEN);

    if (blockIdx.z == 0) {
        float a = 0.0f, bb = 0.0f, p = -1e38f;
        for (int j = 0; j < NCH; ++j) {
            const size_t idx = ((size_t)b * NCH + j) * CDIM + c;
            Lina[idx] = a; Linb[idx] = bb; Linp[idx] = p;
            WKV_COMBINE(a, bb, p, Sfa[idx], Sfb[idx], Sfp[idx], wL);
        }
    } else {
        float a = 0.0f, bb = 0.0f, p = -1e38f;
        for (int j = NCH - 1; j >= 0; --j) {
            const size_t idx = ((size_t)b * NCH + j) * CDIM + c;
            Rina[idx] = a; Rinb[idx] = bb; Rinp[idx] = p;
            WKV_COMBINE(a, bb, p, Sba[idx], Sbb[idx], Sbp[idx], wL);
        }
    }
}

// phase3: combine + fuse z = sr*y, emitting z split to (zh, zl) bf16 for the
// final MFMA GEMM. zh/zl alias xh/xl (dead after the 3 input GEMMs).
__global__ __launch_bounds__(256) void wkv_phase3(
    const float* __restrict__ k, const float* __restrict__ v,
    const float* __restrict__ sr,
    const float* __restrict__ Lina, const float* __restrict__ Linb, const float* __restrict__ Linp,
    const float* __restrict__ Rina, const float* __restrict__ Rinb, const float* __restrict__ Rinp,
    const float* __restrict__ decay, const float* __restrict__ first,
    unsigned short* __restrict__ zh, unsigned short* __restrict__ zl) {
    const int c = blockIdx.x * 256 + threadIdx.x;
    const int j = blockIdx.y;
    const int b = blockIdx.z;
    const float w = decay[c] * (1.0f / (float)TLEN);
    const float u = first[c] * (1.0f / (float)TLEN);

    const size_t base = ((size_t)b * TLEN + (size_t)j * LCH) * CDIM + c;
    float kt[LCH], vt[LCH];
    #pragma unroll
    for (int i = 0; i < LCH; ++i) {
        kt[i] = k[base + (size_t)i * CDIM];
        vt[i] = v[base + (size_t)i * CDIM];
    }

    const size_t idx = ((size_t)b * NCH + j) * CDIM + c;

    float ar[LCH], br[LCH], pr[LCH];
    {
        float a = Rina[idx], bb = Rinb[idx], p = Rinp[idx];
        #pragma unroll
        for (int i = LCH - 1; i >= 0; --i) {
            ar[i] = a; br[i] = bb; pr[i] = p;
            WKV_STEP(a, bb, p, kt[i], vt[i], w);
        }
    }
    {
        float a = Lina[idx], bb = Linb[idx], p = Linp[idx];
        #pragma unroll
        for (int i = 0; i < LCH; ++i) {
            const size_t off = base + (size_t)i * CDIM;
            const float srt = sr[off];
            const float ps = u + kt[i];
            const float q  = fmaxf(fmaxf(p, pr[i]), ps);
            const float eL = __expf(p - q);
            const float eR = __expf(pr[i] - q);
            const float eS = __expf(ps - q);
            const float num = eL * a  + eR * ar[i] + eS * vt[i];
            const float den = eL * bb + eR * br[i] + eS;
            const float zz = srt * (num / den);
            const unsigned short h = f2bf(zz);
            zh[off] = h;
            zl[off] = f2bf(zz - bf2f(h));
            WKV_STEP(a, bb, p, kt[i], vt[i], w);
        }
    }
}

// ---------------------------------------------------------------------------
// Driver. ws layout: [8 weight bf16 planes | per-chunk: k,v,sr f32; 12 state
// planes; xh,xl bf16 (aliased by zh,zl)]. Batch-chunked to fit ws_size.
// ---------------------------------------------------------------------------
extern "C" void kernel_launch(void* const* d_in, const int* in_sizes, int n_in,
                              void* d_out, int out_size, void* d_ws, size_t ws_size,
                              hipStream_t stream) {
    const float* x     = (const float*)d_in[0];
    const float* Wk    = (const float*)d_in[1];
    const float* Wv    = (const float*)d_in[2];
    const float* Wr    = (const float*)d_in[3];
    const float* Wo    = (const float*)d_in[4];
    const float* decay = (const float*)d_in[5];
    const float* first = (const float*)d_in[6];
    float* out = (float*)d_out;

    const size_t WN = (size_t)CDIM * CDIM;
    const size_t wbytes = 8 * WN * sizeof(unsigned short);
    const size_t per_b  = (size_t)TLEN * CDIM * 16 + 12ull * NCH * CDIM * 4;
    if (ws_size < wbytes + per_b) return;
    int nb = (int)((ws_size - wbytes) / per_b);
    if (nb > BSZ) nb = BSZ;

    unsigned short* wsp = (unsigned short*)d_ws;
    unsigned short* Wkh = wsp + 0 * WN; unsigned short* Wkl = wsp + 1 * WN;
    unsigned short* Wvh = wsp + 2 * WN; unsigned short* Wvl = wsp + 3 * WN;
    unsigned short* Wrh = wsp + 4 * WN; unsigned short* Wrl = wsp + 5 * WN;
    unsigned short* Woh = wsp + 6 * WN; unsigned short* Wol = wsp + 7 * WN;

    const size_t NE = (size_t)nb * TLEN * CDIM;
    const size_t NP = (size_t)nb * NCH * CDIM;
    float* fbase = (float*)(wsp + 8 * WN);
    float* kk  = fbase;
    float* vv  = kk + NE;
    float* sr  = vv + NE;
    float* Sfa = sr + NE;               float* Sfb = Sfa + NP;  float* Sfp = Sfb + NP;
    float* Sba = Sfp + NP;              float* Sbb = Sba + NP;  float* Sbp = Sbb + NP;
    float* Lina = Sbp + NP;             float* Linb = Lina + NP; float* Linp = Linb + NP;
    float* Rina = Linp + NP;            float* Rinb = Rina + NP; float* Rinp = Rinb + NP;
    unsigned short* xh = (unsigned short*)(Rinp + NP);
    unsigned short* xl = xh + NE;
    unsigned short* zh = xh;  // alias: phase3 runs after the 3 input GEMMs
    unsigned short* zl = xl;

    split_f32<<<dim3((int)(WN / 1024)), dim3(256), 0, stream>>>(Wk, Wkh, Wkl, (int)(WN / 4));
    split_f32<<<dim3((int)(WN / 1024)), dim3(256), 0, stream>>>(Wv, Wvh, Wvl, (int)(WN / 4));
    split_f32<<<dim3((int)(WN / 1024)), dim3(256), 0, stream>>>(Wr, Wrh, Wrl, (int)(WN / 4));
    split_f32<<<dim3((int)(WN / 1024)), dim3(256), 0, stream>>>(Wo, Woh, Wol, (int)(WN / 4));

    for (int b0 = 0; b0 < BSZ; b0 += nb) {
        const int curb = (BSZ - b0 < nb) ? (BSZ - b0) : nb;
        const int rows = curb * TLEN;
        const float* xc = x   + (size_t)b0 * TLEN * CDIM;
        float*       oc = out + (size_t)b0 * TLEN * CDIM;

        const int n4 = rows * CDIM / 4;
        split_f32<<<dim3(n4 / 256), dim3(256), 0, stream>>>(xc, xh, xl, n4);

        const int mtiles = rows / 256;
        const int nblk = mtiles * 4;           // BN=192: 4 ntiles
        const int mpx  = mtiles / 8;           // mtile-groups per XCD
        gemm_mfma_split<<<dim3(nblk), dim3(512), 0, stream>>>(xh, xl, Wkh, Wkl, kk, mpx, 0);
        gemm_mfma_split<<<dim3(nblk), dim3(512), 0, stream>>>(xh, xl, Wvh, Wvl, vv, mpx, 0);
        gemm_mfma_split<<<dim3(nblk), dim3(512), 0, stream>>>(xh, xl, Wrh, Wrl, sr, mpx, 1);

        wkv_phase1<<<dim3(CDIM / 256, NCH, curb), dim3(256), 0, stream>>>(
            kk, vv, decay, Sfa, Sfb, Sfp, Sba, Sbb, Sbp);
        wkv_phase2<<<dim3(CDIM / 64, curb, 2), dim3(64), 0, stream>>>(
            Sfa, Sfb, Sfp, Sba, Sbb, Sbp, decay,
            Lina, Linb, Linp, Rina, Rinb, Rinp);
        wkv_phase3<<<dim3(CDIM / 256, NCH, curb), dim3(256), 0, stream>>>(
            kk, vv, sr, Lina, Linb, Linp, Rina, Rinb, Rinp, decay, first, zh, zl);

        gemm_mfma_split<<<dim3(nblk), dim3(512), 0, stream>>>(zh, zl, Woh, Wol, oc, mpx, 0);
    }
}

// Round 8
// 251.886 us; speedup vs baseline: 1.3043x; 1.3043x over previous
//
#include <hip/hip_runtime.h>

#define BSZ 8
#define TLEN 2048
#define CDIM 768
#define LCH 16
#define NCH (TLEN / LCH)

typedef __attribute__((ext_vector_type(4))) float f32x4;
typedef __attribute__((ext_vector_type(8))) _Float16 f16x8;   // 8 f16 = 4 VGPRs (MFMA operand)
typedef __attribute__((ext_vector_type(4))) _Float16 f16x4;
typedef __attribute__((ext_vector_type(4))) float float4v;

// async global->LDS, 16B per lane; LDS dest = base + lane*16 (wave-linear)
#define GLD16(g, l)                                                          \
    __builtin_amdgcn_global_load_lds(                                        \
        (const __attribute__((address_space(1))) unsigned int*)(g),          \
        (__attribute__((address_space(3))) unsigned int*)(l), 16, 0, 0)

// ---------------------------------------------------------------------------
// x -> xh' = fp16(x) * 2^-6   (scale exact; cancels against W-planes * 2^6)
// ---------------------------------------------------------------------------
__global__ __launch_bounds__(256) void split_xh(const float* __restrict__ src,
                                                _Float16* __restrict__ hi, int n4) {
    int i = blockIdx.x * 256 + threadIdx.x;
    if (i >= n4) return;
    float4v f = ((const float4v*)src)[i];
    f16x4 h;
    #pragma unroll
    for (int j = 0; j < 4; ++j) h[j] = (_Float16)(f[j] * 0.015625f);
    ((f16x4*)hi)[i] = h;
}

// ---------------------------------------------------------------------------
// W -> Wh' = fp16(W)*2^6,  Wl' = (W - fp16(W))*2^6   (both fp16-normal)
// ---------------------------------------------------------------------------
__global__ __launch_bounds__(256) void split_w(const float* __restrict__ src,
                                               _Float16* __restrict__ hi,
                                               _Float16* __restrict__ lo, int n4) {
    int i = blockIdx.x * 256 + threadIdx.x;
    if (i >= n4) return;
    float4v f = ((const float4v*)src)[i];
    f16x4 h, l;
    #pragma unroll
    for (int j = 0; j < 4; ++j) {
        _Float16 hh = (_Float16)f[j];
        h[j] = (_Float16)((float)hh * 64.0f);
        l[j] = (_Float16)((f[j] - (float)hh) * 64.0f);
    }
    ((f16x4*)hi)[i] = h;
    ((f16x4*)lo)[i] = l;
}

// ---------------------------------------------------------------------------
// fp16 2-pass split GEMM (NT): out[m,n] = sum_k A'[m,k]*(Wh'[n,k]+Wl'[n,k])
// (scales 2^-6 * 2^6 cancel per product; fp32 accum). N=K=CDIM.
// 256x192 tile, BK=32, 8 waves, wave tile 64x96 (4x6 16x16 frags).
// A: 1 plane, 3 LDS bufs (depth-2, vmcnt(4)); B: 2 planes, 2 bufs (vmcnt(0)).
// LDS: 3*16KB + 2*24KB = 96KB. Staging waves 0-3 = A, 4-7 = B.
// Both-sides swizzle involution kq ^= (row>>2)&3 (write: pre-swizzled global
// source; read: swizzled ds_read). mode: 0 f32 out, 1 sigmoid->f16, 2 f16.
// ---------------------------------------------------------------------------
__global__ __launch_bounds__(512, 2) void gemm_mfma_f16(
    const _Float16* __restrict__ A,
    const _Float16* __restrict__ Wh, const _Float16* __restrict__ Wl,
    void* __restrict__ outv, int mpx, int mode) {
    constexpr int K = CDIM, N = CDIM;
    constexpr int NT = K / 32;   // 24
    // A bufs @ 0,16384,32768 (256 rows x 64B); B bufs @ 49152,73728
    // (each: Wh 192x64B @ +0, Wl @ +12288)
    __shared__ __align__(16) char smem[98304];

    const int tid  = threadIdx.x;
    const int lane = tid & 63;
    const int wid  = tid >> 6;

    const int bid = blockIdx.x;
    const int xcd = bid & 7;
    const int lj  = bid >> 3;
    const int m0 = (xcd * mpx + (lj >> 2)) * 256;
    const int n0 = (lj & 3) * 192;

    // ---- staging roles
    const bool isA = (wid < 4);
    const int  sw  = wid & 3;
    const char* gh = (const char*)(isA ? A : Wh);
    const char* gl = (const char*)Wl;
    const int rowstart = isA ? (m0 + sw * 64) : (n0 + sw * 48);
    const int gq = (lane & 3) ^ ((lane >> 4) & 3);      // pre-swizzled k-group
    const size_t gofs = (size_t)(rowstart + (lane >> 2)) * (K * 2) + gq * 16;
    const int lofs = (isA ? sw * 4096 : sw * 3072) + lane * 16;

    auto STAGE = [&](int bufbase, int k0) {
        char* lb = &smem[bufbase] + lofs;
        const char* g = gh + gofs + (size_t)k0 * 2;
        if (isA) {
            #pragma unroll
            for (int q = 0; q < 4; ++q)
                GLD16(g + q * 24576, lb + q * 1024);
        } else {
            const char* g2 = gl + gofs + (size_t)k0 * 2;
            #pragma unroll
            for (int q = 0; q < 3; ++q) {
                GLD16(g  + q * 24576, lb + q * 1024);
                GLD16(g2 + q * 24576, lb + 12288 + q * 1024);
            }
        }
    };

    // ---- compute role
    const int wr = wid >> 1, wc = wid & 1;
    const int rl   = lane & 15;
    const int kofs = (((lane >> 4) ^ ((rl >> 2) & 3)) << 4);

    f32x4 acc[4][6];
    #pragma unroll
    for (int i = 0; i < 4; ++i)
        #pragma unroll
        for (int j = 0; j < 6; ++j)
            acc[i][j] = (f32x4){0.f, 0.f, 0.f, 0.f};

    auto COMPUTE = [&](int ab, int bbase) {
        const char* sb = &smem[0];
        f16x8 a[4];
        #pragma unroll
        for (int fi = 0; fi < 4; ++fi)
            a[fi] = *(const f16x8*)(sb + ab + (wr * 64 + fi * 16 + rl) * 64 + kofs);
        const int boff0 = bbase + (wc * 96 + rl) * 64 + kofs;
        f16x8 bh_c = *(const f16x8*)(sb + boff0);
        f16x8 bl_c = *(const f16x8*)(sb + boff0 + 12288);
        #pragma unroll
        for (int fj = 0; fj < 6; ++fj) {
            f16x8 bh_n = bh_c, bl_n = bl_c;
            if (fj < 5) {
                const int off = bbase + (wc * 96 + (fj + 1) * 16 + rl) * 64 + kofs;
                bh_n = *(const f16x8*)(sb + off);
                bl_n = *(const f16x8*)(sb + off + 12288);
            }
            __builtin_amdgcn_s_setprio(1);
            #pragma unroll
            for (int fi = 0; fi < 4; ++fi)
                acc[fi][fj] = __builtin_amdgcn_mfma_f32_16x16x32_f16(a[fi], bh_c, acc[fi][fj], 0, 0, 0);
            #pragma unroll
            for (int fi = 0; fi < 4; ++fi)
                acc[fi][fj] = __builtin_amdgcn_mfma_f32_16x16x32_f16(a[fi], bl_c, acc[fi][fj], 0, 0, 0);
            __builtin_amdgcn_s_setprio(0);
            bh_c = bh_n; bl_c = bl_n;
        }
    };

    // ---- prologue: A depth-2, B depth-1
    if (isA) {
        STAGE(0, 0); STAGE(16384, 32);
        asm volatile("s_waitcnt vmcnt(4)" ::: "memory");
    } else {
        STAGE(49152, 0);
        asm volatile("s_waitcnt vmcnt(0)" ::: "memory");
    }
    __builtin_amdgcn_s_barrier();

    // ---- main loop, unrolled x6 (buffer cycle LCM(3,2))
    for (int tb = 0; tb < NT; tb += 6) {
        #pragma unroll
        for (int tt = 0; tt < 6; ++tt) {
            const int t = tb + tt;
            if (isA) {
                if (t + 2 < NT) STAGE(((tt + 2) % 3) * 16384, (t + 2) * 32);
            } else {
                if (t + 1 < NT) STAGE(49152 + ((tt + 1) & 1) * 24576, (t + 1) * 32);
            }
            COMPUTE((tt % 3) * 16384, 49152 + (tt & 1) * 24576);
            if (isA && t + 2 < NT) asm volatile("s_waitcnt vmcnt(4)" ::: "memory");
            else                   asm volatile("s_waitcnt vmcnt(0)" ::: "memory");
            __builtin_amdgcn_s_barrier();
        }
    }

    // epilogue: D frag mapping col=lane&15, row=(lane>>4)*4+r
    const int erow = m0 + wr * 64 + ((lane >> 4) << 2);
    const int ecol = n0 + wc * 96 + rl;
    if (mode == 0) {
        float* o = (float*)outv;
        #pragma unroll
        for (int fi = 0; fi < 4; ++fi)
            #pragma unroll
            for (int fj = 0; fj < 6; ++fj)
                #pragma unroll
                for (int r = 0; r < 4; ++r)
                    o[(size_t)(erow + fi * 16 + r) * N + (ecol + fj * 16)] = acc[fi][fj][r];
    } else if (mode == 1) {
        _Float16* o = (_Float16*)outv;
        #pragma unroll
        for (int fi = 0; fi < 4; ++fi)
            #pragma unroll
            for (int fj = 0; fj < 6; ++fj)
                #pragma unroll
                for (int r = 0; r < 4; ++r)
                    o[(size_t)(erow + fi * 16 + r) * N + (ecol + fj * 16)] =
                        (_Float16)(1.0f / (1.0f + __expf(-acc[fi][fj][r])));
    } else {
        _Float16* o = (_Float16*)outv;
        #pragma unroll
        for (int fi = 0; fi < 4; ++fi)
            #pragma unroll
            for (int fj = 0; fj < 6; ++fj)
                #pragma unroll
                for (int r = 0; r < 4; ++r)
                    o[(size_t)(erow + fi * 16 + r) * N + (ecol + fj * 16)] =
                        (_Float16)acc[fi][fj][r];
    }
}

// ---------------------------------------------------------------------------
// WKV (math verified rounds 2-7); k,v,sr now fp16 in memory, f32 in-register.
// ---------------------------------------------------------------------------
#define WKV_STEP(a, bb, p, kt, vt, w)                \
    {                                                \
        const float pn = fmaxf((p) - (w), (kt));     \
        const float e1 = __expf((p) - (w) - pn);     \
        const float e2 = __expf((kt) - pn);          \
        (a)  = e1 * (a)  + e2 * (vt);                \
        (bb) = e1 * (bb) + e2;                       \
        (p)  = pn;                                   \
    }

__global__ __launch_bounds__(256) void wkv_phase1(
    const _Float16* __restrict__ k, const _Float16* __restrict__ v,
    const float* __restrict__ decay,
    float* __restrict__ Sfa, float* __restrict__ Sfb, float* __restrict__ Sfp,
    float* __restrict__ Sba, float* __restrict__ Sbb, float* __restrict__ Sbp) {
    const int c = blockIdx.x * 256 + threadIdx.x;
    const int j = blockIdx.y;
    const int b = blockIdx.z;
    const float w = decay[c] * (1.0f / (float)TLEN);

    const size_t base = ((size_t)b * TLEN + (size_t)j * LCH) * CDIM + c;
    float kt[LCH], vt[LCH];
    #pragma unroll
    for (int i = 0; i < LCH; ++i) {
        kt[i] = (float)k[base + (size_t)i * CDIM];
        vt[i] = (float)v[base + (size_t)i * CDIM];
    }

    const size_t idx = ((size_t)b * NCH + j) * CDIM + c;

    float a = 0.0f, bb = 0.0f, p = -1e38f;
    #pragma unroll
    for (int i = 0; i < LCH; ++i) WKV_STEP(a, bb, p, kt[i], vt[i], w);
    Sfa[idx] = a; Sfb[idx] = bb; Sfp[idx] = p;

    a = 0.0f; bb = 0.0f; p = -1e38f;
    #pragma unroll
    for (int i = LCH - 1; i >= 0; --i) WKV_STEP(a, bb, p, kt[i], vt[i], w);
    Sba[idx] = a; Sbb[idx] = bb; Sbp[idx] = p;
}

#define WKV_COMBINE(a, bb, p, as, bs, ps, wL)        \
    {                                                \
        const float pn = fmaxf((p) - (wL), (ps));    \
        const float e1 = __expf((p) - (wL) - pn);    \
        const float e2 = __expf((ps) - pn);          \
        (a)  = e1 * (a)  + e2 * (as);                \
        (bb) = e1 * (bb) + e2 * (bs);                \
        (p)  = pn;                                   \
    }

// blockIdx.z selects direction (0=forward, 1=backward)
__global__ __launch_bounds__(64) void wkv_phase2(
    const float* __restrict__ Sfa, const float* __restrict__ Sfb, const float* __restrict__ Sfp,
    const float* __restrict__ Sba, const float* __restrict__ Sbb, const float* __restrict__ Sbp,
    const float* __restrict__ decay,
    float* __restrict__ Lina, float* __restrict__ Linb, float* __restrict__ Linp,
    float* __restrict__ Rina, float* __restrict__ Rinb, float* __restrict__ Rinp) {
    const int c = blockIdx.x * 64 + threadIdx.x;
    const int b = blockIdx.y;
    const float wL = decay[c] * ((float)LCH / (float)TLEN);

    if (blockIdx.z == 0) {
        float a = 0.0f, bb = 0.0f, p = -1e38f;
        for (int j = 0; j < NCH; ++j) {
            const size_t idx = ((size_t)b * NCH + j) * CDIM + c;
            Lina[idx] = a; Linb[idx] = bb; Linp[idx] = p;
            WKV_COMBINE(a, bb, p, Sfa[idx], Sfb[idx], Sfp[idx], wL);
        }
    } else {
        float a = 0.0f, bb = 0.0f, p = -1e38f;
        for (int j = NCH - 1; j >= 0; --j) {
            const size_t idx = ((size_t)b * NCH + j) * CDIM + c;
            Rina[idx] = a; Rinb[idx] = bb; Rinp[idx] = p;
            WKV_COMBINE(a, bb, p, Sba[idx], Sbb[idx], Sbp[idx], wL);
        }
    }
}

// phase3: combine + fuse z = sr*y; z written as fp16 * 2^-6 (final GEMM's A').
// zh aliases xh (dead after the 3 input GEMMs).
__global__ __launch_bounds__(256) void wkv_phase3(
    const _Float16* __restrict__ k, const _Float16* __restrict__ v,
    const _Float16* __restrict__ sr,
    const float* __restrict__ Lina, const float* __restrict__ Linb, const float* __restrict__ Linp,
    const float* __restrict__ Rina, const float* __restrict__ Rinb, const float* __restrict__ Rinp,
    const float* __restrict__ decay, const float* __restrict__ first,
    _Float16* __restrict__ zh) {
    const int c = blockIdx.x * 256 + threadIdx.x;
    const int j = blockIdx.y;
    const int b = blockIdx.z;
    const float w = decay[c] * (1.0f / (float)TLEN);
    const float u = first[c] * (1.0f / (float)TLEN);

    const size_t base = ((size_t)b * TLEN + (size_t)j * LCH) * CDIM + c;
    float kt[LCH], vt[LCH];
    #pragma unroll
    for (int i = 0; i < LCH; ++i) {
        kt[i] = (float)k[base + (size_t)i * CDIM];
        vt[i] = (float)v[base + (size_t)i * CDIM];
    }

    const size_t idx = ((size_t)b * NCH + j) * CDIM + c;

    float ar[LCH], br[LCH], pr[LCH];
    {
        float a = Rina[idx], bb = Rinb[idx], p = Rinp[idx];
        #pragma unroll
        for (int i = LCH - 1; i >= 0; --i) {
            ar[i] = a; br[i] = bb; pr[i] = p;
            WKV_STEP(a, bb, p, kt[i], vt[i], w);
        }
    }
    {
        float a = Lina[idx], bb = Linb[idx], p = Linp[idx];
        #pragma unroll
        for (int i = 0; i < LCH; ++i) {
            const size_t off = base + (size_t)i * CDIM;
            const float srt = (float)sr[off];
            const float ps = u + kt[i];
            const float q  = fmaxf(fmaxf(p, pr[i]), ps);
            const float eL = __expf(p - q);
            const float eR = __expf(pr[i] - q);
            const float eS = __expf(ps - q);
            const float num = eL * a  + eR * ar[i] + eS * vt[i];
            const float den = eL * bb + eR * br[i] + eS;
            const float zz = srt * (num / den);
            zh[off] = (_Float16)(zz * 0.015625f);
            WKV_STEP(a, bb, p, kt[i], vt[i], w);
        }
    }
}

// ---------------------------------------------------------------------------
// Driver. ws layout: [8 weight f16 planes | 12 state f32 planes | kh vh srh
// xh f16 planes (zh aliases xh)]. Batch-chunked to fit ws_size.
// ---------------------------------------------------------------------------
extern "C" void kernel_launch(void* const* d_in, const int* in_sizes, int n_in,
                              void* d_out, int out_size, void* d_ws, size_t ws_size,
                              hipStream_t stream) {
    const float* x     = (const float*)d_in[0];
    const float* Wk    = (const float*)d_in[1];
    const float* Wv    = (const float*)d_in[2];
    const float* Wr    = (const float*)d_in[3];
    const float* Wo    = (const float*)d_in[4];
    const float* decay = (const float*)d_in[5];
    const float* first = (const float*)d_in[6];
    float* out = (float*)d_out;

    const size_t WN = (size_t)CDIM * CDIM;
    const size_t wbytes = 8 * WN * sizeof(_Float16);                 // 9.44 MB
    const size_t per_b  = (size_t)TLEN * CDIM * 8 + 12ull * NCH * CDIM * 4; // 17.3 MB
    if (ws_size < wbytes + per_b) return;
    int nb = (int)((ws_size - wbytes) / per_b);
    if (nb > BSZ) nb = BSZ;

    _Float16* wsp = (_Float16*)d_ws;
    _Float16* Wkh = wsp + 0 * WN; _Float16* Wkl = wsp + 1 * WN;
    _Float16* Wvh = wsp + 2 * WN; _Float16* Wvl = wsp + 3 * WN;
    _Float16* Wrh = wsp + 4 * WN; _Float16* Wrl = wsp + 5 * WN;
    _Float16* Woh = wsp + 6 * WN; _Float16* Wol = wsp + 7 * WN;

    const size_t NE = (size_t)nb * TLEN * CDIM;
    const size_t NP = (size_t)nb * NCH * CDIM;
    float* Sfa = (float*)(wsp + 8 * WN);
    float* Sfb = Sfa + NP;  float* Sfp = Sfb + NP;
    float* Sba = Sfp + NP;  float* Sbb = Sba + NP;  float* Sbp = Sbb + NP;
    float* Lina = Sbp + NP; float* Linb = Lina + NP; float* Linp = Linb + NP;
    float* Rina = Linp + NP; float* Rinb = Rina + NP; float* Rinp = Rinb + NP;
    _Float16* kh  = (_Float16*)(Rinp + NP);
    _Float16* vh  = kh + NE;
    _Float16* srh = vh + NE;
    _Float16* xh  = srh + NE;
    _Float16* zh  = xh;   // alias: phase3 runs after the 3 input GEMMs

    split_w<<<dim3((int)(WN / 1024)), dim3(256), 0, stream>>>(Wk, Wkh, Wkl, (int)(WN / 4));
    split_w<<<dim3((int)(WN / 1024)), dim3(256), 0, stream>>>(Wv, Wvh, Wvl, (int)(WN / 4));
    split_w<<<dim3((int)(WN / 1024)), dim3(256), 0, stream>>>(Wr, Wrh, Wrl, (int)(WN / 4));
    split_w<<<dim3((int)(WN / 1024)), dim3(256), 0, stream>>>(Wo, Woh, Wol, (int)(WN / 4));

    for (int b0 = 0; b0 < BSZ; b0 += nb) {
        const int curb = (BSZ - b0 < nb) ? (BSZ - b0) : nb;
        const int rows = curb * TLEN;
        const float* xc = x   + (size_t)b0 * TLEN * CDIM;
        float*       oc = out + (size_t)b0 * TLEN * CDIM;

        const int n4 = rows * CDIM / 4;
        split_xh<<<dim3(n4 / 256), dim3(256), 0, stream>>>(xc, xh, n4);

        const int mtiles = rows / 256;
        const int nblk = mtiles * 4;           // BN=192: 4 ntiles
        const int mpx  = mtiles / 8;           // mtile-groups per XCD
        gemm_mfma_f16<<<dim3(nblk), dim3(512), 0, stream>>>(xh, Wkh, Wkl, kh,  mpx, 2);
        gemm_mfma_f16<<<dim3(nblk), dim3(512), 0, stream>>>(xh, Wvh, Wvl, vh,  mpx, 2);
        gemm_mfma_f16<<<dim3(nblk), dim3(512), 0, stream>>>(xh, Wrh, Wrl, srh, mpx, 1);

        wkv_phase1<<<dim3(CDIM / 256, NCH, curb), dim3(256), 0, stream>>>(
            kh, vh, decay, Sfa, Sfb, Sfp, Sba, Sbb, Sbp);
        wkv_phase2<<<dim3(CDIM / 64, curb, 2), dim3(64), 0, stream>>>(
            Sfa, Sfb, Sfp, Sba, Sbb, Sbp, decay,
            Lina, Linb, Linp, Rina, Rinb, Rinp);
        wkv_phase3<<<dim3(CDIM / 256, NCH, curb), dim3(256), 0, stream>>>(
            kh, vh, srh, Lina, Linb, Linp, Rina, Rinb, Rinp, decay, first, zh);

        gemm_mfma_f16<<<dim3(nblk), dim3(512), 0, stream>>>(zh, Woh, Wol, oc, mpx, 0);
    }
}

// Round 9
// 195.049 us; speedup vs baseline: 1.6843x; 1.2914x over previous
//
#include <hip/hip_runtime.h>

#define BSZ 8
#define TLEN 2048
#define CDIM 768
#define LCH 16
#define NCH (TLEN / LCH)

typedef __attribute__((ext_vector_type(4))) float f32x4;
typedef __attribute__((ext_vector_type(8))) _Float16 f16x8;   // 8 f16 = 4 VGPRs (MFMA operand)
typedef __attribute__((ext_vector_type(4))) _Float16 f16x4;
typedef __attribute__((ext_vector_type(4))) float float4v;

// async global->LDS, 16B per lane; LDS dest = base + lane*16 (wave-linear)
#define GLD16(g, l)                                                          \
    __builtin_amdgcn_global_load_lds(                                        \
        (const __attribute__((address_space(1))) unsigned int*)(g),          \
        (__attribute__((address_space(3))) unsigned int*)(l), 16, 0, 0)

// ---------------------------------------------------------------------------
// x -> xh' = fp16(x) * 2^-6   (scale exact; cancels against W-planes * 2^6)
// ---------------------------------------------------------------------------
__global__ __launch_bounds__(256) void split_xh(const float* __restrict__ src,
                                                _Float16* __restrict__ hi, int n4) {
    int i = blockIdx.x * 256 + threadIdx.x;
    if (i >= n4) return;
    float4v f = ((const float4v*)src)[i];
    f16x4 h;
    #pragma unroll
    for (int j = 0; j < 4; ++j) h[j] = (_Float16)(f[j] * 0.015625f);
    ((f16x4*)hi)[i] = h;
}

// W -> Wh' = fp16(W)*2^6 only (single-pass weights)
__global__ __launch_bounds__(256) void split_w1(const float* __restrict__ src,
                                                _Float16* __restrict__ hi, int n4) {
    int i = blockIdx.x * 256 + threadIdx.x;
    if (i >= n4) return;
    float4v f = ((const float4v*)src)[i];
    f16x4 h;
    #pragma unroll
    for (int j = 0; j < 4; ++j) h[j] = (_Float16)((float)((_Float16)f[j]) * 64.0f);
    ((f16x4*)hi)[i] = h;
}

// W -> Wh' = fp16(W)*2^6,  Wl' = (W - fp16(W))*2^6  (2-pass weights, Wo only)
__global__ __launch_bounds__(256) void split_w(const float* __restrict__ src,
                                               _Float16* __restrict__ hi,
                                               _Float16* __restrict__ lo, int n4) {
    int i = blockIdx.x * 256 + threadIdx.x;
    if (i >= n4) return;
    float4v f = ((const float4v*)src)[i];
    f16x4 h, l;
    #pragma unroll
    for (int j = 0; j < 4; ++j) {
        _Float16 hh = (_Float16)f[j];
        h[j] = (_Float16)((float)hh * 64.0f);
        l[j] = (_Float16)((f[j] - (float)hh) * 64.0f);
    }
    ((f16x4*)hi)[i] = h;
    ((f16x4*)lo)[i] = l;
}

// ---------------------------------------------------------------------------
// Single-pass fp16 GEMM (NT), BK=64: out[m,n] = sum_k A'[m,k]*W'[n,k].
// 256x192 tile, 8 waves, wave tile 64x96. NT = 768/64 = 12 K-steps.
// LDS rows are 128B; swizzle: cell (row, c16) holds global k-group c^(row&7).
//   write: linear LDS dest, global source pre-swizzled g=(lane&7)^(lane>>3)
//   read:  chunk = (ks*4 + lane>>4) ^ (rl&7)   -> uniform 8/bank (floor)
// A: 3 bufs @0/32768/65536 (depth-2, vmcnt(8), waves 0-3, 8 loads/stage)
// B: 2 bufs @98304/122880 (depth-1, vmcnt(0), waves 4-7, 6 loads/stage)
// mode 1: sigmoid -> f16; else f16 store.
// ---------------------------------------------------------------------------
__global__ __launch_bounds__(512, 2) void gemm_f16_1p(
    const _Float16* __restrict__ A, const _Float16* __restrict__ W,
    _Float16* __restrict__ out, int mpx, int mode) {
    constexpr int K = CDIM, N = CDIM;
    constexpr int NT = K / 64;   // 12
    __shared__ __align__(16) char smem[147456];

    const int tid  = threadIdx.x;
    const int lane = tid & 63;
    const int wid  = tid >> 6;

    const int bid = blockIdx.x;
    const int xcd = bid & 7;
    const int lj  = bid >> 3;
    const int m0 = (xcd * mpx + (lj >> 2)) * 256;
    const int n0 = (lj & 3) * 192;

    // ---- staging roles
    const bool isA = (wid < 4);
    const int  sw  = wid & 3;
    const char* gsrc = (const char*)(isA ? A : W);
    const int row0 = isA ? (m0 + sw * 64) : (n0 + sw * 48);
    const int gq = (lane & 7) ^ (lane >> 3);           // pre-swizzled k-group
    const size_t gofs = (size_t)(row0 + (lane >> 3)) * (K * 2) + gq * 16;
    const int lofs = (isA ? sw * 8192 : sw * 6144) + lane * 16;

    auto STAGE = [&](int bufbase, int t) {             // t = 64-elem k-tile
        char* lb = &smem[bufbase] + lofs;
        const char* g = gsrc + gofs + (size_t)t * 128;
        if (isA) {
            #pragma unroll
            for (int q = 0; q < 8; ++q)                // 8-row stripes
                GLD16(g + q * 12288, lb + q * 1024);
        } else {
            #pragma unroll
            for (int q = 0; q < 6; ++q)
                GLD16(g + q * 12288, lb + q * 1024);
        }
    };

    // ---- compute role
    const int wr = wid >> 1, wc = wid & 1;
    const int rl = lane & 15;
    const int k0ofs = ((((lane >> 4) + 0) ^ (rl & 7)) << 4);
    const int k1ofs = ((((lane >> 4) + 4) ^ (rl & 7)) << 4);

    f32x4 acc[4][6];
    #pragma unroll
    for (int i = 0; i < 4; ++i)
        #pragma unroll
        for (int j = 0; j < 6; ++j)
            acc[i][j] = (f32x4){0.f, 0.f, 0.f, 0.f};

    auto COMPUTE = [&](int ab, int bbase) {
        const char* sb = &smem[0];
        #pragma unroll
        for (int ks = 0; ks < 2; ++ks) {
            const int kq = ks ? k1ofs : k0ofs;
            f16x8 a[4];
            #pragma unroll
            for (int fi = 0; fi < 4; ++fi)
                a[fi] = *(const f16x8*)(sb + ab + (wr * 64 + fi * 16 + rl) * 128 + kq);
            f16x8 bc = *(const f16x8*)(sb + bbase + (wc * 96 + rl) * 128 + kq);
            #pragma unroll
            for (int fj = 0; fj < 6; ++fj) {
                f16x8 bn = bc;
                if (fj < 5)
                    bn = *(const f16x8*)(sb + bbase + (wc * 96 + (fj + 1) * 16 + rl) * 128 + kq);
                __builtin_amdgcn_s_setprio(1);
                #pragma unroll
                for (int fi = 0; fi < 4; ++fi)
                    acc[fi][fj] = __builtin_amdgcn_mfma_f32_16x16x32_f16(a[fi], bc, acc[fi][fj], 0, 0, 0);
                __builtin_amdgcn_s_setprio(0);
                bc = bn;
            }
        }
    };

    // ---- prologue: A depth-2, B depth-1
    if (isA) {
        STAGE(0, 0); STAGE(32768, 1);
        asm volatile("s_waitcnt vmcnt(8)" ::: "memory");
    } else {
        STAGE(98304, 0);
        asm volatile("s_waitcnt vmcnt(0)" ::: "memory");
    }
    __builtin_amdgcn_s_barrier();

    // ---- main loop, unrolled x6 (buffer cycle LCM(3,2)); NT=12
    for (int tb = 0; tb < NT; tb += 6) {
        #pragma unroll
        for (int tt = 0; tt < 6; ++tt) {
            const int t = tb + tt;
            if (isA) {
                if (t + 2 < NT) STAGE(((tt + 2) % 3) * 32768, t + 2);
            } else {
                if (t + 1 < NT) STAGE(98304 + ((tt + 1) & 1) * 24576, t + 1);
            }
            COMPUTE((tt % 3) * 32768, 98304 + (tt & 1) * 24576);
            if (isA && t + 2 < NT) asm volatile("s_waitcnt vmcnt(8)" ::: "memory");
            else                   asm volatile("s_waitcnt vmcnt(0)" ::: "memory");
            __builtin_amdgcn_s_barrier();
        }
    }

    // epilogue: D frag mapping col=lane&15, row=(lane>>4)*4+r
    const int erow = m0 + wr * 64 + ((lane >> 4) << 2);
    const int ecol = n0 + wc * 96 + rl;
    if (mode == 1) {
        #pragma unroll
        for (int fi = 0; fi < 4; ++fi)
            #pragma unroll
            for (int fj = 0; fj < 6; ++fj)
                #pragma unroll
                for (int r = 0; r < 4; ++r)
                    out[(size_t)(erow + fi * 16 + r) * N + (ecol + fj * 16)] =
                        (_Float16)(1.0f / (1.0f + __expf(-acc[fi][fj][r])));
    } else {
        #pragma unroll
        for (int fi = 0; fi < 4; ++fi)
            #pragma unroll
            for (int fj = 0; fj < 6; ++fj)
                #pragma unroll
                for (int r = 0; r < 4; ++r)
                    out[(size_t)(erow + fi * 16 + r) * N + (ecol + fj * 16)] =
                        (_Float16)acc[fi][fj][r];
    }
}

// ---------------------------------------------------------------------------
// fp16 2-pass split GEMM (NT), BK=32 — unchanged round-8 kernel (Wo only).
// ---------------------------------------------------------------------------
__global__ __launch_bounds__(512, 2) void gemm_mfma_f16(
    const _Float16* __restrict__ A,
    const _Float16* __restrict__ Wh, const _Float16* __restrict__ Wl,
    void* __restrict__ outv, int mpx, int mode) {
    constexpr int K = CDIM, N = CDIM;
    constexpr int NT = K / 32;   // 24
    __shared__ __align__(16) char smem[98304];

    const int tid  = threadIdx.x;
    const int lane = tid & 63;
    const int wid  = tid >> 6;

    const int bid = blockIdx.x;
    const int xcd = bid & 7;
    const int lj  = bid >> 3;
    const int m0 = (xcd * mpx + (lj >> 2)) * 256;
    const int n0 = (lj & 3) * 192;

    const bool isA = (wid < 4);
    const int  sw  = wid & 3;
    const char* gh = (const char*)(isA ? A : Wh);
    const char* gl = (const char*)Wl;
    const int rowstart = isA ? (m0 + sw * 64) : (n0 + sw * 48);
    const int gq = (lane & 3) ^ ((lane >> 4) & 3);
    const size_t gofs = (size_t)(rowstart + (lane >> 2)) * (K * 2) + gq * 16;
    const int lofs = (isA ? sw * 4096 : sw * 3072) + lane * 16;

    auto STAGE = [&](int bufbase, int k0) {
        char* lb = &smem[bufbase] + lofs;
        const char* g = gh + gofs + (size_t)k0 * 2;
        if (isA) {
            #pragma unroll
            for (int q = 0; q < 4; ++q)
                GLD16(g + q * 24576, lb + q * 1024);
        } else {
            const char* g2 = gl + gofs + (size_t)k0 * 2;
            #pragma unroll
            for (int q = 0; q < 3; ++q) {
                GLD16(g  + q * 24576, lb + q * 1024);
                GLD16(g2 + q * 24576, lb + 12288 + q * 1024);
            }
        }
    };

    const int wr = wid >> 1, wc = wid & 1;
    const int rl   = lane & 15;
    const int kofs = (((lane >> 4) ^ ((rl >> 2) & 3)) << 4);

    f32x4 acc[4][6];
    #pragma unroll
    for (int i = 0; i < 4; ++i)
        #pragma unroll
        for (int j = 0; j < 6; ++j)
            acc[i][j] = (f32x4){0.f, 0.f, 0.f, 0.f};

    auto COMPUTE = [&](int ab, int bbase) {
        const char* sb = &smem[0];
        f16x8 a[4];
        #pragma unroll
        for (int fi = 0; fi < 4; ++fi)
            a[fi] = *(const f16x8*)(sb + ab + (wr * 64 + fi * 16 + rl) * 64 + kofs);
        const int boff0 = bbase + (wc * 96 + rl) * 64 + kofs;
        f16x8 bh_c = *(const f16x8*)(sb + boff0);
        f16x8 bl_c = *(const f16x8*)(sb + boff0 + 12288);
        #pragma unroll
        for (int fj = 0; fj < 6; ++fj) {
            f16x8 bh_n = bh_c, bl_n = bl_c;
            if (fj < 5) {
                const int off = bbase + (wc * 96 + (fj + 1) * 16 + rl) * 64 + kofs;
                bh_n = *(const f16x8*)(sb + off);
                bl_n = *(const f16x8*)(sb + off + 12288);
            }
            __builtin_amdgcn_s_setprio(1);
            #pragma unroll
            for (int fi = 0; fi < 4; ++fi)
                acc[fi][fj] = __builtin_amdgcn_mfma_f32_16x16x32_f16(a[fi], bh_c, acc[fi][fj], 0, 0, 0);
            #pragma unroll
            for (int fi = 0; fi < 4; ++fi)
                acc[fi][fj] = __builtin_amdgcn_mfma_f32_16x16x32_f16(a[fi], bl_c, acc[fi][fj], 0, 0, 0);
            __builtin_amdgcn_s_setprio(0);
            bh_c = bh_n; bl_c = bl_n;
        }
    };

    if (isA) {
        STAGE(0, 0); STAGE(16384, 32);
        asm volatile("s_waitcnt vmcnt(4)" ::: "memory");
    } else {
        STAGE(49152, 0);
        asm volatile("s_waitcnt vmcnt(0)" ::: "memory");
    }
    __builtin_amdgcn_s_barrier();

    for (int tb = 0; tb < NT; tb += 6) {
        #pragma unroll
        for (int tt = 0; tt < 6; ++tt) {
            const int t = tb + tt;
            if (isA) {
                if (t + 2 < NT) STAGE(((tt + 2) % 3) * 16384, (t + 2) * 32);
            } else {
                if (t + 1 < NT) STAGE(49152 + ((tt + 1) & 1) * 24576, (t + 1) * 32);
            }
            COMPUTE((tt % 3) * 16384, 49152 + (tt & 1) * 24576);
            if (isA && t + 2 < NT) asm volatile("s_waitcnt vmcnt(4)" ::: "memory");
            else                   asm volatile("s_waitcnt vmcnt(0)" ::: "memory");
            __builtin_amdgcn_s_barrier();
        }
    }

    const int erow = m0 + wr * 64 + ((lane >> 4) << 2);
    const int ecol = n0 + wc * 96 + rl;
    if (mode == 0) {
        float* o = (float*)outv;
        #pragma unroll
        for (int fi = 0; fi < 4; ++fi)
            #pragma unroll
            for (int fj = 0; fj < 6; ++fj)
                #pragma unroll
                for (int r = 0; r < 4; ++r)
                    o[(size_t)(erow + fi * 16 + r) * N + (ecol + fj * 16)] = acc[fi][fj][r];
    } else {
        _Float16* o = (_Float16*)outv;
        #pragma unroll
        for (int fi = 0; fi < 4; ++fi)
            #pragma unroll
            for (int fj = 0; fj < 6; ++fj)
                #pragma unroll
                for (int r = 0; r < 4; ++r)
                    o[(size_t)(erow + fi * 16 + r) * N + (ecol + fj * 16)] =
                        (_Float16)acc[fi][fj][r];
    }
}

// ---------------------------------------------------------------------------
// WKV (math verified rounds 2-8); k,v,sr fp16 in memory, f32 in-register.
// ---------------------------------------------------------------------------
#define WKV_STEP(a, bb, p, kt, vt, w)                \
    {                                                \
        const float pn = fmaxf((p) - (w), (kt));     \
        const float e1 = __expf((p) - (w) - pn);     \
        const float e2 = __expf((kt) - pn);          \
        (a)  = e1 * (a)  + e2 * (vt);                \
        (bb) = e1 * (bb) + e2;                       \
        (p)  = pn;                                   \
    }

__global__ __launch_bounds__(256) void wkv_phase1(
    const _Float16* __restrict__ k, const _Float16* __restrict__ v,
    const float* __restrict__ decay,
    float* __restrict__ Sfa, float* __restrict__ Sfb, float* __restrict__ Sfp,
    float* __restrict__ Sba, float* __restrict__ Sbb, float* __restrict__ Sbp) {
    const int c = blockIdx.x * 256 + threadIdx.x;
    const int j = blockIdx.y;
    const int b = blockIdx.z;
    const float w = decay[c] * (1.0f / (float)TLEN);

    const size_t base = ((size_t)b * TLEN + (size_t)j * LCH) * CDIM + c;
    float kt[LCH], vt[LCH];
    #pragma unroll
    for (int i = 0; i < LCH; ++i) {
        kt[i] = (float)k[base + (size_t)i * CDIM];
        vt[i] = (float)v[base + (size_t)i * CDIM];
    }

    const size_t idx = ((size_t)b * NCH + j) * CDIM + c;

    float a = 0.0f, bb = 0.0f, p = -1e38f;
    #pragma unroll
    for (int i = 0; i < LCH; ++i) WKV_STEP(a, bb, p, kt[i], vt[i], w);
    Sfa[idx] = a; Sfb[idx] = bb; Sfp[idx] = p;

    a = 0.0f; bb = 0.0f; p = -1e38f;
    #pragma unroll
    for (int i = LCH - 1; i >= 0; --i) WKV_STEP(a, bb, p, kt[i], vt[i], w);
    Sba[idx] = a; Sbb[idx] = bb; Sbp[idx] = p;
}

#define WKV_COMBINE(a, bb, p, as, bs, ps, wL)        \
    {                                                \
        const float pn = fmaxf((p) - (wL), (ps));    \
        const float e1 = __expf((p) - (wL) - pn);    \
        const float e2 = __expf((ps) - pn);          \
        (a)  = e1 * (a)  + e2 * (as);                \
        (bb) = e1 * (bb) + e2 * (bs);                \
        (p)  = pn;                                   \
    }

// blockIdx.z = direction. Software-pipelined: groups of 4, static dbuf (A/B).
__global__ __launch_bounds__(64) void wkv_phase2(
    const float* __restrict__ Sfa, const float* __restrict__ Sfb, const float* __restrict__ Sfp,
    const float* __restrict__ Sba, const float* __restrict__ Sbb, const float* __restrict__ Sbp,
    const float* __restrict__ decay,
    float* __restrict__ Lina, float* __restrict__ Linb, float* __restrict__ Linp,
    float* __restrict__ Rina, float* __restrict__ Rinb, float* __restrict__ Rinp) {
    const int c = blockIdx.x * 64 + threadIdx.x;
    const int b = blockIdx.y;
    const int dir = blockIdx.z;
    const float wL = decay[c] * ((float)LCH / (float)TLEN);

    const float* Sa = dir ? Sba : Sfa;
    const float* Sb = dir ? Sbb : Sfb;
    const float* Sp = dir ? Sbp : Sfp;
    float* Oa = dir ? Rina : Lina;
    float* Ob = dir ? Rinb : Linb;
    float* Op = dir ? Rinp : Linp;

    const size_t base = (size_t)b * NCH * CDIM + c;
    auto IDX = [&](int j) {
        return base + (size_t)(dir ? (NCH - 1 - j) : j) * CDIM;
    };

    float gaA[4], gbA[4], gpA[4], gaB[4], gbB[4], gpB[4];
    #pragma unroll
    for (int u = 0; u < 4; ++u) {
        const size_t id = IDX(u);
        gaA[u] = Sa[id]; gbA[u] = Sb[id]; gpA[u] = Sp[id];
    }
    float a = 0.0f, bb = 0.0f, p = -1e38f;

    for (int jg = 0; jg < NCH; jg += 8) {
        #pragma unroll
        for (int u = 0; u < 4; ++u) {
            const size_t id = IDX(jg + 4 + u);
            gaB[u] = Sa[id]; gbB[u] = Sb[id]; gpB[u] = Sp[id];
        }
        #pragma unroll
        for (int u = 0; u < 4; ++u) {
            const size_t id = IDX(jg + u);
            Oa[id] = a; Ob[id] = bb; Op[id] = p;
            WKV_COMBINE(a, bb, p, gaA[u], gbA[u], gpA[u], wL);
        }
        if (jg + 8 < NCH) {
            #pragma unroll
            for (int u = 0; u < 4; ++u) {
                const size_t id = IDX(jg + 8 + u);
                gaA[u] = Sa[id]; gbA[u] = Sb[id]; gpA[u] = Sp[id];
            }
        }
        #pragma unroll
        for (int u = 0; u < 4; ++u) {
            const size_t id = IDX(jg + 4 + u);
            Oa[id] = a; Ob[id] = bb; Op[id] = p;
            WKV_COMBINE(a, bb, p, gaB[u], gbB[u], gpB[u], wL);
        }
    }
}

// phase3: combine + fuse z = sr*y; z written fp16 * 2^-6 (final GEMM's A').
__global__ __launch_bounds__(256) void wkv_phase3(
    const _Float16* __restrict__ k, const _Float16* __restrict__ v,
    const _Float16* __restrict__ sr,
    const float* __restrict__ Lina, const float* __restrict__ Linb, const float* __restrict__ Linp,
    const float* __restrict__ Rina, const float* __restrict__ Rinb, const float* __restrict__ Rinp,
    const float* __restrict__ decay, const float* __restrict__ first,
    _Float16* __restrict__ zh) {
    const int c = blockIdx.x * 256 + threadIdx.x;
    const int j = blockIdx.y;
    const int b = blockIdx.z;
    const float w = decay[c] * (1.0f / (float)TLEN);
    const float u = first[c] * (1.0f / (float)TLEN);

    const size_t base = ((size_t)b * TLEN + (size_t)j * LCH) * CDIM + c;
    float kt[LCH], vt[LCH];
    #pragma unroll
    for (int i = 0; i < LCH; ++i) {
        kt[i] = (float)k[base + (size_t)i * CDIM];
        vt[i] = (float)v[base + (size_t)i * CDIM];
    }

    const size_t idx = ((size_t)b * NCH + j) * CDIM + c;

    float ar[LCH], br[LCH], pr[LCH];
    {
        float a = Rina[idx], bb = Rinb[idx], p = Rinp[idx];
        #pragma unroll
        for (int i = LCH - 1; i >= 0; --i) {
            ar[i] = a; br[i] = bb; pr[i] = p;
            WKV_STEP(a, bb, p, kt[i], vt[i], w);
        }
    }
    {
        float a = Lina[idx], bb = Linb[idx], p = Linp[idx];
        #pragma unroll
        for (int i = 0; i < LCH; ++i) {
            const size_t off = base + (size_t)i * CDIM;
            const float srt = (float)sr[off];
            const float ps = u + kt[i];
            const float q  = fmaxf(fmaxf(p, pr[i]), ps);
            const float eL = __expf(p - q);
            const float eR = __expf(pr[i] - q);
            const float eS = __expf(ps - q);
            const float num = eL * a  + eR * ar[i] + eS * vt[i];
            const float den = eL * bb + eR * br[i] + eS;
            const float zz = srt * (num / den);
            zh[off] = (_Float16)(zz * 0.015625f);
            WKV_STEP(a, bb, p, kt[i], vt[i], w);
        }
    }
}

// ---------------------------------------------------------------------------
// Driver. ws: [5 weight f16 planes | 12 state f32 planes | kh vh srh xh f16
// planes (zh aliases xh)]. Batch-chunked to fit ws_size.
// ---------------------------------------------------------------------------
extern "C" void kernel_launch(void* const* d_in, const int* in_sizes, int n_in,
                              void* d_out, int out_size, void* d_ws, size_t ws_size,
                              hipStream_t stream) {
    const float* x     = (const float*)d_in[0];
    const float* Wk    = (const float*)d_in[1];
    const float* Wv    = (const float*)d_in[2];
    const float* Wr    = (const float*)d_in[3];
    const float* Wo    = (const float*)d_in[4];
    const float* decay = (const float*)d_in[5];
    const float* first = (const float*)d_in[6];
    float* out = (float*)d_out;

    const size_t WN = (size_t)CDIM * CDIM;
    const size_t wbytes = 5 * WN * sizeof(_Float16);
    const size_t per_b  = (size_t)TLEN * CDIM * 8 + 12ull * NCH * CDIM * 4; // 17.3 MB
    if (ws_size < wbytes + per_b) return;
    int nb = (int)((ws_size - wbytes) / per_b);
    if (nb > BSZ) nb = BSZ;

    _Float16* wsp = (_Float16*)d_ws;
    _Float16* Wkh = wsp + 0 * WN;
    _Float16* Wvh = wsp + 1 * WN;
    _Float16* Wrh = wsp + 2 * WN;
    _Float16* Woh = wsp + 3 * WN;
    _Float16* Wol = wsp + 4 * WN;

    const size_t NE = (size_t)nb * TLEN * CDIM;
    const size_t NP = (size_t)nb * NCH * CDIM;
    float* Sfa = (float*)(wsp + 5 * WN);
    float* Sfb = Sfa + NP;  float* Sfp = Sfb + NP;
    float* Sba = Sfp + NP;  float* Sbb = Sba + NP;  float* Sbp = Sbb + NP;
    float* Lina = Sbp + NP; float* Linb = Lina + NP; float* Linp = Linb + NP;
    float* Rina = Linp + NP; float* Rinb = Rina + NP; float* Rinp = Rinb + NP;
    _Float16* kh  = (_Float16*)(Rinp + NP);
    _Float16* vh  = kh + NE;
    _Float16* srh = vh + NE;
    _Float16* xh  = srh + NE;
    _Float16* zh  = xh;   // alias: phase3 runs after the 3 input GEMMs

    split_w1<<<dim3((int)(WN / 1024)), dim3(256), 0, stream>>>(Wk, Wkh, (int)(WN / 4));
    split_w1<<<dim3((int)(WN / 1024)), dim3(256), 0, stream>>>(Wv, Wvh, (int)(WN / 4));
    split_w1<<<dim3((int)(WN / 1024)), dim3(256), 0, stream>>>(Wr, Wrh, (int)(WN / 4));
    split_w <<<dim3((int)(WN / 1024)), dim3(256), 0, stream>>>(Wo, Woh, Wol, (int)(WN / 4));

    for (int b0 = 0; b0 < BSZ; b0 += nb) {
        const int curb = (BSZ - b0 < nb) ? (BSZ - b0) : nb;
        const int rows = curb * TLEN;
        const float* xc = x   + (size_t)b0 * TLEN * CDIM;
        float*       oc = out + (size_t)b0 * TLEN * CDIM;

        const int n4 = rows * CDIM / 4;
        split_xh<<<dim3(n4 / 256), dim3(256), 0, stream>>>(xc, xh, n4);

        const int mtiles = rows / 256;
        const int nblk = mtiles * 4;           // BN=192: 4 ntiles
        const int mpx  = mtiles / 8;           // mtile-groups per XCD
        gemm_f16_1p<<<dim3(nblk), dim3(512), 0, stream>>>(xh, Wkh, kh,  mpx, 2);
        gemm_f16_1p<<<dim3(nblk), dim3(512), 0, stream>>>(xh, Wvh, vh,  mpx, 2);
        gemm_f16_1p<<<dim3(nblk), dim3(512), 0, stream>>>(xh, Wrh, srh, mpx, 1);

        wkv_phase1<<<dim3(CDIM / 256, NCH, curb), dim3(256), 0, stream>>>(
            kh, vh, decay, Sfa, Sfb, Sfp, Sba, Sbb, Sbp);
        wkv_phase2<<<dim3(CDIM / 64, curb, 2), dim3(64), 0, stream>>>(
            Sfa, Sfb, Sfp, Sba, Sbb, Sbp, decay,
            Lina, Linb, Linp, Rina, Rinb, Rinp);
        wkv_phase3<<<dim3(CDIM / 256, NCH, curb), dim3(256), 0, stream>>>(
            kh, vh, srh, Lina, Linb, Linp, Rina, Rinb, Rinp, decay, first, zh);

        gemm_mfma_f16<<<dim3(nblk), dim3(512), 0, stream>>>(zh, Woh, Wol, oc, mpx, 0);
    }
}

// Round 10
// 173.635 us; speedup vs baseline: 1.8921x; 1.1233x over previous
//
#include <hip/hip_runtime.h>

#define BSZ 8
#define TLEN 2048
#define CDIM 768
#define LCH 16
#define NCH (TLEN / LCH)

typedef __attribute__((ext_vector_type(4))) float f32x4;
typedef __attribute__((ext_vector_type(8))) _Float16 f16x8;   // 8 f16 = 4 VGPRs (MFMA operand)
typedef __attribute__((ext_vector_type(4))) _Float16 f16x4;
typedef __attribute__((ext_vector_type(4))) float float4v;

// async global->LDS, 16B per lane; LDS dest = base + lane*16 (wave-linear)
#define GLD16(g, l)                                                          \
    __builtin_amdgcn_global_load_lds(                                        \
        (const __attribute__((address_space(1))) unsigned int*)(g),          \
        (__attribute__((address_space(3))) unsigned int*)(l), 16, 0, 0)

// ---------------------------------------------------------------------------
// f32 -> f16 cast, 4 elements/thread (x and weight planes)
// ---------------------------------------------------------------------------
__global__ __launch_bounds__(256) void split_f16(const float* __restrict__ src,
                                                 _Float16* __restrict__ dst, int n4) {
    int i = blockIdx.x * 256 + threadIdx.x;
    if (i >= n4) return;
    float4v f = ((const float4v*)src)[i];
    f16x4 h;
    #pragma unroll
    for (int j = 0; j < 4; ++j) h[j] = (_Float16)f[j];
    ((f16x4*)dst)[i] = h;
}

// ---------------------------------------------------------------------------
// Single-pass fp16 GEMM (NT), BK=64: out[m,n] = sum_k A[m,k]*W[n,k].
// W is a concatenated plane of NTL*192 rows (NTL ntiles of 192 cols).
// 256x192 tile, 8 waves, wave tile 64x96. NT = 768/64 = 12 K-steps.
// LDS rows are 128B; swizzle: cell (row, c16) holds global k-group c^(row&7).
//   write: linear LDS dest, global source pre-swizzled g=(lane&7)^(lane>>3)
//   read:  chunk = (ks*4 + lane>>4) ^ (rl&7)
// A: 3 bufs @0/32768/65536 (depth-2, vmcnt(8), waves 0-3, 8 loads/stage)
// B: 2 bufs @98304/122880 (depth-1, vmcnt(0), waves 4-7, 6 loads/stage)
// Output: buf = nt/4 selects o0/o1/o2 (f16); sigmoid applied for nt>=sig_from;
// if of32 != null, f32 store to of32 instead (Wo GEMM).
// Block decode: bid = xcd + 8*lj; lj = mt*NTL + nt; m0 = (xcd*mpx + mt)*256.
// ---------------------------------------------------------------------------
__global__ __launch_bounds__(512, 2) void gemm_f16_1p(
    const _Float16* __restrict__ A, const _Float16* __restrict__ W,
    _Float16* __restrict__ o0, _Float16* __restrict__ o1, _Float16* __restrict__ o2,
    float* __restrict__ of32, int mpx, int NTL, int sig_from) {
    constexpr int K = CDIM, N = CDIM;
    constexpr int NT = K / 64;   // 12
    __shared__ __align__(16) char smem[147456];

    const int tid  = threadIdx.x;
    const int lane = tid & 63;
    const int wid  = tid >> 6;

    const int bid = blockIdx.x;
    const int xcd = bid & 7;
    const int lj  = bid >> 3;
    const int mt  = lj / NTL;
    const int nt  = lj - mt * NTL;
    const int m0  = (xcd * mpx + mt) * 256;
    const int n0  = nt * 192;          // row offset into concatenated W

    // ---- staging roles
    const bool isA = (wid < 4);
    const int  sw  = wid & 3;
    const char* gsrc = (const char*)(isA ? A : W);
    const int row0 = isA ? (m0 + sw * 64) : (n0 + sw * 48);
    const int gq = (lane & 7) ^ (lane >> 3);           // pre-swizzled k-group
    const size_t gofs = (size_t)(row0 + (lane >> 3)) * (K * 2) + gq * 16;
    const int lofs = (isA ? sw * 8192 : sw * 6144) + lane * 16;

    auto STAGE = [&](int bufbase, int t) {             // t = 64-elem k-tile
        char* lb = &smem[bufbase] + lofs;
        const char* g = gsrc + gofs + (size_t)t * 128;
        if (isA) {
            #pragma unroll
            for (int q = 0; q < 8; ++q)                // 8-row stripes
                GLD16(g + q * 12288, lb + q * 1024);
        } else {
            #pragma unroll
            for (int q = 0; q < 6; ++q)
                GLD16(g + q * 12288, lb + q * 1024);
        }
    };

    // ---- compute role
    const int wr = wid >> 1, wc = wid & 1;
    const int rl = lane & 15;
    const int k0ofs = ((((lane >> 4) + 0) ^ (rl & 7)) << 4);
    const int k1ofs = ((((lane >> 4) + 4) ^ (rl & 7)) << 4);

    f32x4 acc[4][6];
    #pragma unroll
    for (int i = 0; i < 4; ++i)
        #pragma unroll
        for (int j = 0; j < 6; ++j)
            acc[i][j] = (f32x4){0.f, 0.f, 0.f, 0.f};

    auto COMPUTE = [&](int ab, int bbase) {
        const char* sb = &smem[0];
        #pragma unroll
        for (int ks = 0; ks < 2; ++ks) {
            const int kq = ks ? k1ofs : k0ofs;
            f16x8 a[4];
            #pragma unroll
            for (int fi = 0; fi < 4; ++fi)
                a[fi] = *(const f16x8*)(sb + ab + (wr * 64 + fi * 16 + rl) * 128 + kq);
            f16x8 bc = *(const f16x8*)(sb + bbase + (wc * 96 + rl) * 128 + kq);
            #pragma unroll
            for (int fj = 0; fj < 6; ++fj) {
                f16x8 bn = bc;
                if (fj < 5)
                    bn = *(const f16x8*)(sb + bbase + (wc * 96 + (fj + 1) * 16 + rl) * 128 + kq);
                __builtin_amdgcn_s_setprio(1);
                #pragma unroll
                for (int fi = 0; fi < 4; ++fi)
                    acc[fi][fj] = __builtin_amdgcn_mfma_f32_16x16x32_f16(a[fi], bc, acc[fi][fj], 0, 0, 0);
                __builtin_amdgcn_s_setprio(0);
                bc = bn;
            }
        }
    };

    // ---- prologue: A depth-2, B depth-1
    if (isA) {
        STAGE(0, 0); STAGE(32768, 1);
        asm volatile("s_waitcnt vmcnt(8)" ::: "memory");
    } else {
        STAGE(98304, 0);
        asm volatile("s_waitcnt vmcnt(0)" ::: "memory");
    }
    __builtin_amdgcn_s_barrier();

    // ---- main loop, unrolled x6 (buffer cycle LCM(3,2)); NT=12
    for (int tb = 0; tb < NT; tb += 6) {
        #pragma unroll
        for (int tt = 0; tt < 6; ++tt) {
            const int t = tb + tt;
            if (isA) {
                if (t + 2 < NT) STAGE(((tt + 2) % 3) * 32768, t + 2);
            } else {
                if (t + 1 < NT) STAGE(98304 + ((tt + 1) & 1) * 24576, t + 1);
            }
            COMPUTE((tt % 3) * 32768, 98304 + (tt & 1) * 24576);
            if (isA && t + 2 < NT) asm volatile("s_waitcnt vmcnt(8)" ::: "memory");
            else                   asm volatile("s_waitcnt vmcnt(0)" ::: "memory");
            __builtin_amdgcn_s_barrier();
        }
    }

    // epilogue: D frag mapping col=lane&15, row=(lane>>4)*4+r
    const int buf   = nt >> 2;
    const int ncol0 = (nt & 3) * 192;
    const int erow = m0 + wr * 64 + ((lane >> 4) << 2);
    const int ecol = ncol0 + wc * 96 + rl;
    if (of32) {
        #pragma unroll
        for (int fi = 0; fi < 4; ++fi)
            #pragma unroll
            for (int fj = 0; fj < 6; ++fj)
                #pragma unroll
                for (int r = 0; r < 4; ++r)
                    of32[(size_t)(erow + fi * 16 + r) * N + (ecol + fj * 16)] = acc[fi][fj][r];
    } else {
        _Float16* o = (buf == 0) ? o0 : ((buf == 1) ? o1 : o2);
        if (nt >= sig_from) {
            #pragma unroll
            for (int fi = 0; fi < 4; ++fi)
                #pragma unroll
                for (int fj = 0; fj < 6; ++fj)
                    #pragma unroll
                    for (int r = 0; r < 4; ++r)
                        o[(size_t)(erow + fi * 16 + r) * N + (ecol + fj * 16)] =
                            (_Float16)(1.0f / (1.0f + __expf(-acc[fi][fj][r])));
        } else {
            #pragma unroll
            for (int fi = 0; fi < 4; ++fi)
                #pragma unroll
                for (int fj = 0; fj < 6; ++fj)
                    #pragma unroll
                    for (int r = 0; r < 4; ++r)
                        o[(size_t)(erow + fi * 16 + r) * N + (ecol + fj * 16)] =
                            (_Float16)acc[fi][fj][r];
        }
    }
}

// ---------------------------------------------------------------------------
// WKV (math verified rounds 2-9); k,v,sr fp16 in memory, f32 in-register.
// ---------------------------------------------------------------------------
#define WKV_STEP(a, bb, p, kt, vt, w)                \
    {                                                \
        const float pn = fmaxf((p) - (w), (kt));     \
        const float e1 = __expf((p) - (w) - pn);     \
        const float e2 = __expf((kt) - pn);          \
        (a)  = e1 * (a)  + e2 * (vt);                \
        (bb) = e1 * (bb) + e2;                       \
        (p)  = pn;                                   \
    }

__global__ __launch_bounds__(256) void wkv_phase1(
    const _Float16* __restrict__ k, const _Float16* __restrict__ v,
    const float* __restrict__ decay,
    float* __restrict__ Sfa, float* __restrict__ Sfb, float* __restrict__ Sfp,
    float* __restrict__ Sba, float* __restrict__ Sbb, float* __restrict__ Sbp) {
    const int c = blockIdx.x * 256 + threadIdx.x;
    const int j = blockIdx.y;
    const int b = blockIdx.z;
    const float w = decay[c] * (1.0f / (float)TLEN);

    const size_t base = ((size_t)b * TLEN + (size_t)j * LCH) * CDIM + c;
    float kt[LCH], vt[LCH];
    #pragma unroll
    for (int i = 0; i < LCH; ++i) {
        kt[i] = (float)k[base + (size_t)i * CDIM];
        vt[i] = (float)v[base + (size_t)i * CDIM];
    }

    const size_t idx = ((size_t)b * NCH + j) * CDIM + c;

    float a = 0.0f, bb = 0.0f, p = -1e38f;
    #pragma unroll
    for (int i = 0; i < LCH; ++i) WKV_STEP(a, bb, p, kt[i], vt[i], w);
    Sfa[idx] = a; Sfb[idx] = bb; Sfp[idx] = p;

    a = 0.0f; bb = 0.0f; p = -1e38f;
    #pragma unroll
    for (int i = LCH - 1; i >= 0; --i) WKV_STEP(a, bb, p, kt[i], vt[i], w);
    Sba[idx] = a; Sbb[idx] = bb; Sbp[idx] = p;
}

#define WKV_COMBINE(a, bb, p, as, bs, ps, wL)        \
    {                                                \
        const float pn = fmaxf((p) - (wL), (ps));    \
        const float e1 = __expf((p) - (wL) - pn);    \
        const float e2 = __expf((ps) - pn);          \
        (a)  = e1 * (a)  + e2 * (as);                \
        (bb) = e1 * (bb) + e2 * (bs);                \
        (p)  = pn;                                   \
    }

// blockIdx.z = direction. Software-pipelined: groups of 4, static dbuf (A/B).
__global__ __launch_bounds__(64) void wkv_phase2(
    const float* __restrict__ Sfa, const float* __restrict__ Sfb, const float* __restrict__ Sfp,
    const float* __restrict__ Sba, const float* __restrict__ Sbb, const float* __restrict__ Sbp,
    const float* __restrict__ decay,
    float* __restrict__ Lina, float* __restrict__ Linb, float* __restrict__ Linp,
    float* __restrict__ Rina, float* __restrict__ Rinb, float* __restrict__ Rinp) {
    const int c = blockIdx.x * 64 + threadIdx.x;
    const int b = blockIdx.y;
    const int dir = blockIdx.z;
    const float wL = decay[c] * ((float)LCH / (float)TLEN);

    const float* Sa = dir ? Sba : Sfa;
    const float* Sb = dir ? Sbb : Sfb;
    const float* Sp = dir ? Sbp : Sfp;
    float* Oa = dir ? Rina : Lina;
    float* Ob = dir ? Rinb : Linb;
    float* Op = dir ? Rinp : Linp;

    const size_t base = (size_t)b * NCH * CDIM + c;
    auto IDX = [&](int j) {
        return base + (size_t)(dir ? (NCH - 1 - j) : j) * CDIM;
    };

    float gaA[4], gbA[4], gpA[4], gaB[4], gbB[4], gpB[4];
    #pragma unroll
    for (int u = 0; u < 4; ++u) {
        const size_t id = IDX(u);
        gaA[u] = Sa[id]; gbA[u] = Sb[id]; gpA[u] = Sp[id];
    }
    float a = 0.0f, bb = 0.0f, p = -1e38f;

    for (int jg = 0; jg < NCH; jg += 8) {
        #pragma unroll
        for (int u = 0; u < 4; ++u) {
            const size_t id = IDX(jg + 4 + u);
            gaB[u] = Sa[id]; gbB[u] = Sb[id]; gpB[u] = Sp[id];
        }
        #pragma unroll
        for (int u = 0; u < 4; ++u) {
            const size_t id = IDX(jg + u);
            Oa[id] = a; Ob[id] = bb; Op[id] = p;
            WKV_COMBINE(a, bb, p, gaA[u], gbA[u], gpA[u], wL);
        }
        if (jg + 8 < NCH) {
            #pragma unroll
            for (int u = 0; u < 4; ++u) {
                const size_t id = IDX(jg + 8 + u);
                gaA[u] = Sa[id]; gbA[u] = Sb[id]; gpA[u] = Sp[id];
            }
        }
        #pragma unroll
        for (int u = 0; u < 4; ++u) {
            const size_t id = IDX(jg + 4 + u);
            Oa[id] = a; Ob[id] = bb; Op[id] = p;
            WKV_COMBINE(a, bb, p, gaB[u], gbB[u], gpB[u], wL);
        }
    }
}

// phase3: combine + fuse z = sr*y; z written fp16 (final GEMM's A).
__global__ __launch_bounds__(256) void wkv_phase3(
    const _Float16* __restrict__ k, const _Float16* __restrict__ v,
    const _Float16* __restrict__ sr,
    const float* __restrict__ Lina, const float* __restrict__ Linb, const float* __restrict__ Linp,
    const float* __restrict__ Rina, const float* __restrict__ Rinb, const float* __restrict__ Rinp,
    const float* __restrict__ decay, const float* __restrict__ first,
    _Float16* __restrict__ zh) {
    const int c = blockIdx.x * 256 + threadIdx.x;
    const int j = blockIdx.y;
    const int b = blockIdx.z;
    const float w = decay[c] * (1.0f / (float)TLEN);
    const float u = first[c] * (1.0f / (float)TLEN);

    const size_t base = ((size_t)b * TLEN + (size_t)j * LCH) * CDIM + c;
    float kt[LCH], vt[LCH];
    #pragma unroll
    for (int i = 0; i < LCH; ++i) {
        kt[i] = (float)k[base + (size_t)i * CDIM];
        vt[i] = (float)v[base + (size_t)i * CDIM];
    }

    const size_t idx = ((size_t)b * NCH + j) * CDIM + c;

    float ar[LCH], br[LCH], pr[LCH];
    {
        float a = Rina[idx], bb = Rinb[idx], p = Rinp[idx];
        #pragma unroll
        for (int i = LCH - 1; i >= 0; --i) {
            ar[i] = a; br[i] = bb; pr[i] = p;
            WKV_STEP(a, bb, p, kt[i], vt[i], w);
        }
    }
    {
        float a = Lina[idx], bb = Linb[idx], p = Linp[idx];
        #pragma unroll
        for (int i = 0; i < LCH; ++i) {
            const size_t off = base + (size_t)i * CDIM;
            const float srt = (float)sr[off];
            const float ps = u + kt[i];
            const float q  = fmaxf(fmaxf(p, pr[i]), ps);
            const float eL = __expf(p - q);
            const float eR = __expf(pr[i] - q);
            const float eS = __expf(ps - q);
            const float num = eL * a  + eR * ar[i] + eS * vt[i];
            const float den = eL * bb + eR * br[i] + eS;
            zh[off] = (_Float16)(srt * (num / den));
            WKV_STEP(a, bb, p, kt[i], vt[i], w);
        }
    }
}

// ---------------------------------------------------------------------------
// Driver. ws: [Wcat 3*WN f16 | Woh WN f16 | 12 state f32 planes | kh vh srh
// xh f16 planes (zh aliases xh)]. Batch-chunked to fit ws_size.
// ---------------------------------------------------------------------------
extern "C" void kernel_launch(void* const* d_in, const int* in_sizes, int n_in,
                              void* d_out, int out_size, void* d_ws, size_t ws_size,
                              hipStream_t stream) {
    const float* x     = (const float*)d_in[0];
    const float* Wk    = (const float*)d_in[1];
    const float* Wv    = (const float*)d_in[2];
    const float* Wr    = (const float*)d_in[3];
    const float* Wo    = (const float*)d_in[4];
    const float* decay = (const float*)d_in[5];
    const float* first = (const float*)d_in[6];
    float* out = (float*)d_out;

    const size_t WN = (size_t)CDIM * CDIM;
    const size_t wbytes = 4 * WN * sizeof(_Float16);
    const size_t per_b  = (size_t)TLEN * CDIM * 8 + 12ull * NCH * CDIM * 4; // 17.3 MB
    if (ws_size < wbytes + per_b) return;
    int nb = (int)((ws_size - wbytes) / per_b);
    if (nb > BSZ) nb = BSZ;

    _Float16* wsp  = (_Float16*)d_ws;
    _Float16* Wcat = wsp;                 // rows 0-767 Wk, 768-1535 Wv, 1536-2303 Wr
    _Float16* Woh  = wsp + 3 * WN;

    const size_t NE = (size_t)nb * TLEN * CDIM;
    const size_t NP = (size_t)nb * NCH * CDIM;
    float* Sfa = (float*)(wsp + 4 * WN);
    float* Sfb = Sfa + NP;  float* Sfp = Sfb + NP;
    float* Sba = Sfp + NP;  float* Sbb = Sba + NP;  float* Sbp = Sbb + NP;
    float* Lina = Sbp + NP; float* Linb = Lina + NP; float* Linp = Linb + NP;
    float* Rina = Linp + NP; float* Rinb = Rina + NP; float* Rinp = Rinb + NP;
    _Float16* kh  = (_Float16*)(Rinp + NP);
    _Float16* vh  = kh + NE;
    _Float16* srh = vh + NE;
    _Float16* xh  = srh + NE;
    _Float16* zh  = xh;   // alias: phase3 runs after the merged input GEMM

    split_f16<<<dim3((int)(WN / 1024)), dim3(256), 0, stream>>>(Wk, Wcat + 0 * WN, (int)(WN / 4));
    split_f16<<<dim3((int)(WN / 1024)), dim3(256), 0, stream>>>(Wv, Wcat + 1 * WN, (int)(WN / 4));
    split_f16<<<dim3((int)(WN / 1024)), dim3(256), 0, stream>>>(Wr, Wcat + 2 * WN, (int)(WN / 4));
    split_f16<<<dim3((int)(WN / 1024)), dim3(256), 0, stream>>>(Wo, Woh, (int)(WN / 4));

    for (int b0 = 0; b0 < BSZ; b0 += nb) {
        const int curb = (BSZ - b0 < nb) ? (BSZ - b0) : nb;
        const int rows = curb * TLEN;
        const float* xc = x   + (size_t)b0 * TLEN * CDIM;
        float*       oc = out + (size_t)b0 * TLEN * CDIM;

        const int n4 = rows * CDIM / 4;
        split_f16<<<dim3(n4 / 256), dim3(256), 0, stream>>>(xc, xh, n4);

        const int mtiles = rows / 256;
        const int mpx    = mtiles / 8;     // mtiles per XCD (= curb)

        // merged k|v|sr GEMM: N = 2304 (12 ntiles), sigmoid on nt>=8 (sr)
        gemm_f16_1p<<<dim3(mtiles * 12), dim3(512), 0, stream>>>(
            xh, Wcat, kh, vh, srh, nullptr, mpx, 12, 8);

        wkv_phase1<<<dim3(CDIM / 256, NCH, curb), dim3(256), 0, stream>>>(
            kh, vh, decay, Sfa, Sfb, Sfp, Sba, Sbb, Sbp);
        wkv_phase2<<<dim3(CDIM / 64, curb, 2), dim3(64), 0, stream>>>(
            Sfa, Sfb, Sfp, Sba, Sbb, Sbp, decay,
            Lina, Linb, Linp, Rina, Rinb, Rinp);
        wkv_phase3<<<dim3(CDIM / 256, NCH, curb), dim3(256), 0, stream>>>(
            kh, vh, srh, Lina, Linb, Linp, Rina, Rinb, Rinp, decay, first, zh);

        // Wo GEMM: N = 768 (4 ntiles), f32 output
        gemm_f16_1p<<<dim3(mtiles * 4), dim3(512), 0, stream>>>(
            zh, Woh, nullptr, nullptr, nullptr, oc, mpx, 4, 99);
    }
}